// Round 9
// baseline (1354.669 us; speedup 1.0000x reference)
//
#include <hip/hip_runtime.h>
#include <hip/hip_bf16.h>

// Problem constants
#define BTOT 8192
#define TSTEPS 50
#define FIN 25
#define H1C 200
#define G1C 800     // 4*H1
#define H2C 100
#define KPAD 256    // K = 200(h) + 25(x) padded to 256
#define BM 32       // batch rows per block
#define AST 264     // As row stride in bf16 elems (528 B)
#define TSTRIDE 1024 // frag-units (bf16x8) per tile = 16(kt)*32(l31)*2(h5)

typedef __bf16 bf16_t;
typedef __bf16 bf16x8 __attribute__((ext_vector_type(8)));
typedef float f32x16 __attribute__((ext_vector_type(16)));

__device__ __forceinline__ float sigm(float x) {
  float e = __builtin_amdgcn_exp2f(-1.4426950408889634f * x);
  return __builtin_amdgcn_rcpf(1.0f + e);
}
__device__ __forceinline__ float tanha(float x) {
  float e = __builtin_amdgcn_exp2f(-2.885390081777927f * x);
  return 2.0f * __builtin_amdgcn_rcpf(1.0f + e) - 1.0f;
}

// Wcat layout: frag-major [tile(25)][kt(16)][l31(32)][h5(2)][elem(8)] bf16.
// Flat elem index = tile*8192 + kt*512 + l31*16 + h5*8 + elem
//   (frag-unit index = tile*1024 + kt*64 + l31*2 + h5).
// Lane (l31,h5) of tile's kt-frag supplies B[k=kt*16+h5*8+e][col=tile*32+l31].
// Column c=tile*32+l31 maps to unit u=tile*8+(l31>>2), gate g=l31&3 (i,f,g,o),
// original W row = g*200+u. K layout: [W_hh1(200) | W_ih1(25) | zeros(31)]
__global__ void prep_kernel(const float* __restrict__ Wih1, const float* __restrict__ Whh1,
                            const float* __restrict__ bih1, const float* __restrict__ bhh1,
                            bf16_t* __restrict__ Wcat, float* __restrict__ bcat) {
  int tid = blockIdx.x * blockDim.x + threadIdx.x;
  for (int e = tid; e < G1C * KPAD; e += gridDim.x * blockDim.x) {
    int elem = e & 7;
    int h5p = (e >> 3) & 1;
    int l31p = (e >> 4) & 31;
    int kt = (e >> 9) & 15;
    int tile = e >> 13;
    int k = kt * 16 + h5p * 8 + elem;
    int u = tile * 8 + (l31p >> 2);
    int gate = l31p & 3;
    int orig = gate * 200 + u;
    float v = 0.f;
    if (k < 200) v = Whh1[orig * 200 + k];
    else if (k < 225) v = Wih1[orig * 25 + (k - 200)];
    Wcat[e] = (bf16_t)v;
  }
  if (tid < G1C) {
    int n = tid;
    int tile = n >> 5, local = n & 31;
    int u = tile * 8 + (local >> 2);
    int gate = local & 3;
    int orig = gate * 200 + u;
    bcat[n] = bih1[orig] + bhh1[orig];
  }
}

// Process one 32x32 output tile: 16 MFMA on current B regs, refill B for
// next_tile (WAR after MFMA -> compiler interleaves load<->MFMA), then the
// LSTM cell update + h-publish for this tile's 8 units.
__device__ __forceinline__ void proc_tile(
    const bf16_t* __restrict__ Ac, bf16_t* __restrict__ An,
    const bf16x8* __restrict__ Wv, bf16x8 (&b)[16],
    int this_tile, int next_tile, float bvv, float* cc,
    int l31, int h5, int p, int uq) {
  f32x16 A;
  #pragma unroll
  for (int q = 0; q < 16; ++q) A[q] = bvv;
  #pragma unroll
  for (int kt = 0; kt < 16; ++kt) {
    bf16x8 a = *(const bf16x8*)(&Ac[l31 * AST + kt * 16 + h5 * 8]);
    A = __builtin_amdgcn_mfma_f32_32x32x16_bf16(a, b[kt], A, 0, 0, 0);
  }
  {
    const bf16x8* wp = Wv + next_tile * TSTRIDE + (l31 * 2 + h5);
    #pragma unroll
    for (int kt = 0; kt < 16; ++kt) b[kt] = wp[kt * 64];
  }
  int u = this_tile * 8 + uq;
  #pragma unroll
  for (int i = 0; i < 4; ++i) {
    float s0 = A[i], s1 = A[4 + i], s2 = A[8 + i], s3 = A[12 + i];
    float own = (p == 0) ? s0 : (p == 1) ? s1 : (p == 2) ? s2 : s3;
    int q1 = p ^ 1;
    float t1 = (q1 == 0) ? s0 : (q1 == 1) ? s1 : (q1 == 2) ? s2 : s3;
    float r1 = __shfl_xor(t1, 1);
    int q2 = p ^ 2;
    float t2 = (q2 == 0) ? s0 : (q2 == 1) ? s1 : (q2 == 2) ? s2 : s3;
    float r2 = __shfl_xor(t2, 2);
    int q3 = p ^ 3;
    float t3 = (q3 == 0) ? s0 : (q3 == 1) ? s1 : (q3 == 2) ? s2 : s3;
    float r3 = __shfl_xor(t3, 3);
    float vi = (p == 0) ? own : (p == 1) ? r1 : (p == 2) ? r2 : r3;
    float vf = (p == 0) ? r1 : (p == 1) ? own : (p == 2) ? r3 : r2;
    float vg = (p == 0) ? r2 : (p == 1) ? r3 : (p == 2) ? own : r1;
    float vo = (p == 0) ? r3 : (p == 1) ? r2 : (p == 2) ? r1 : own;
    float ig = sigm(vi), fg = sigm(vf), gg = tanha(vg), og = sigm(vo);
    float cn = fg * cc[i] + ig * gg;
    cc[i] = cn;
    float hv = og * tanha(cn);
    int r = 8 * p + 4 * h5 + i;
    An[r * AST + u] = (bf16_t)hv;
  }
}

__global__ __launch_bounds__(1024, 4) void lstm_main(
    const float* __restrict__ x,
    const bf16_t* __restrict__ Wcat, const float* __restrict__ bcat,
    const float* __restrict__ h10, const float* __restrict__ c10,
    const float* __restrict__ Wih2, const float* __restrict__ Whh2,
    const float* __restrict__ bih2, const float* __restrict__ bhh2,
    const float* __restrict__ fcw, const float* __restrict__ fcb,
    const float* __restrict__ h20, const float* __restrict__ c20,
    float* __restrict__ out) {

  __shared__ __align__(16) bf16_t As[2][BM * AST];  // double-buffered A: h(0..199)|x(200..224)|0
  __shared__ float h2s[BM * 101];
  __shared__ float c2s[BM * 101];
  __shared__ float facc[BM];

  const int tid = threadIdx.x;
  const int lane = tid & 63;
  const int wid = tid >> 6;               // 0..15
  const int gbase = blockIdx.x * BM;

  // 25 N-tiles over 16 waves: waves 0-8 own 2 tiles, waves 9-15 own 1
  const int tcnt = (wid < 9) ? 2 : 1;
  const int tstart = (wid < 9) ? 2 * wid : wid + 9;

  const int l31 = lane & 31;
  const int h5 = lane >> 5;               // k-chunk of A/B fragment
  const int p = lane & 3;                 // gate owned by this lane (quad position)
  const int uq = l31 >> 2;                // unit-in-tile 0..7

  // ---- prologue: zero both A buffers, stage h0 + x0 ----
  for (int i = tid; i < 2 * BM * AST; i += 1024) ((bf16_t*)As)[i] = (bf16_t)0.f;
  __syncthreads();
  for (int i = tid; i < BM * H1C; i += 1024) {
    int r = i / H1C, u = i - r * H1C;
    As[0][r * AST + u] = (bf16_t)h10[(gbase + r) * H1C + u];
  }
  if (tid < BM * FIN) {
    int r = tid / FIN, f = tid - (tid / FIN) * FIN;
    As[0][r * AST + 200 + f] = (bf16_t)x[(size_t)(gbase + r) * (TSTEPS * FIN) + f];
  }

  float bv[2];
  float cc[8];
  #pragma unroll
  for (int nt = 0; nt < 2; ++nt) {
    bv[nt] = 0.f;
    #pragma unroll
    for (int i = 0; i < 4; ++i) cc[nt * 4 + i] = 0.f;
    if (nt < tcnt) {
      bv[nt] = bcat[(tstart + nt) * 32 + l31];
      int u = (tstart + nt) * 8 + uq;
      #pragma unroll
      for (int i = 0; i < 4; ++i) {
        int r = 8 * p + 4 * h5 + i;
        cc[nt * 4 + i] = c10[(gbase + r) * H1C + u];
      }
    }
  }

  // x prefetch slot (800 elems over 1024 threads -> 1 slot)
  const bool xvld = (tid < BM * FIN);
  unsigned xg = 0, xlo = 0;
  if (xvld) {
    int r = tid / FIN, f = tid - (tid / FIN) * FIN;
    xg = (unsigned)(gbase + r) * (TSTEPS * FIN) + f;
    xlo = (unsigned)(r * AST + 200 + f);
  }
  __syncthreads();

  const bf16x8* __restrict__ Wv = (const bf16x8*)Wcat;   // frag units of 16B

  // single B buffer; initial fill for this wave's first tile
  bf16x8 b[16];
  {
    const bf16x8* wp = Wv + tstart * TSTRIDE + (l31 * 2 + h5);
    #pragma unroll
    for (int kt = 0; kt < 16; ++kt) b[kt] = wp[kt * 64];
  }

  // ---- recurrence ----
  #pragma unroll 1
  for (int t = 0; t < TSTEPS; ++t) {
    const bf16_t* __restrict__ Ac = As[t & 1];
    bf16_t* __restrict__ An = As[(t & 1) ^ 1];

    float xr = 0.f;
    if (t < TSTEPS - 1 && xvld) xr = x[xg + (unsigned)(t + 1) * FIN];

    // tile 0 (all waves); B refilled for tile1 (or next step's tile0)
    proc_tile(Ac, An, Wv, b, tstart, (tcnt == 2) ? tstart + 1 : tstart,
              bv[0], cc + 0, l31, h5, p, uq);
    if (tcnt == 2)
      proc_tile(Ac, An, Wv, b, tstart + 1, tstart,
                bv[1], cc + 4, l31, h5, p, uq);

    if (t < TSTEPS - 1 && xvld) An[xlo] = (bf16_t)xr;
    __syncthreads();   // next-step buffer fully published
  }

  // final h1 lives in As[0] (TSTEPS even), cols 0..199, stride AST
  const bf16_t* __restrict__ hf = As[0];

  // ---- fused layer-2 (single LSTM cell on final h1) + FC + sigmoid ----
  for (int i = tid; i < BM * H2C; i += 1024) {
    int r = i / H2C, u = i - r * H2C;
    h2s[r * 101 + u] = h20[(gbase + r) * H2C + u];
    c2s[r * 101 + u] = c20[(gbase + r) * H2C + u];
  }
  if (tid < BM) facc[tid] = 0.f;
  __syncthreads();

  const float fcb0 = fcb[0];
  for (int i = tid; i < BM * H2C; i += 1024) {
    int u = i >> 5;       // 0..99 (consecutive threads share u -> W rows broadcast)
    int r = i & 31;
    float a0 = bih2[u] + bhh2[u];
    float a1 = bih2[100 + u] + bhh2[100 + u];
    float a2 = bih2[200 + u] + bhh2[200 + u];
    float a3 = bih2[300 + u] + bhh2[300 + u];
    const float4* w0 = (const float4*)(Wih2 + (0 * H2C + u) * H1C);
    const float4* w1 = (const float4*)(Wih2 + (1 * H2C + u) * H1C);
    const float4* w2 = (const float4*)(Wih2 + (2 * H2C + u) * H1C);
    const float4* w3 = (const float4*)(Wih2 + (3 * H2C + u) * H1C);
    #pragma unroll 5
    for (int k4 = 0; k4 < 50; ++k4) {
      float hk0 = (float)hf[r * AST + 4 * k4 + 0];
      float hk1 = (float)hf[r * AST + 4 * k4 + 1];
      float hk2 = (float)hf[r * AST + 4 * k4 + 2];
      float hk3 = (float)hf[r * AST + 4 * k4 + 3];
      float4 wv;
      wv = w0[k4]; a0 += hk0 * wv.x + hk1 * wv.y + hk2 * wv.z + hk3 * wv.w;
      wv = w1[k4]; a1 += hk0 * wv.x + hk1 * wv.y + hk2 * wv.z + hk3 * wv.w;
      wv = w2[k4]; a2 += hk0 * wv.x + hk1 * wv.y + hk2 * wv.z + hk3 * wv.w;
      wv = w3[k4]; a3 += hk0 * wv.x + hk1 * wv.y + hk2 * wv.z + hk3 * wv.w;
    }
    const float4* v0 = (const float4*)(Whh2 + (0 * H2C + u) * H2C);
    const float4* v1 = (const float4*)(Whh2 + (1 * H2C + u) * H2C);
    const float4* v2 = (const float4*)(Whh2 + (2 * H2C + u) * H2C);
    const float4* v3 = (const float4*)(Whh2 + (3 * H2C + u) * H2C);
    #pragma unroll 5
    for (int k4 = 0; k4 < 25; ++k4) {
      float hk0 = h2s[r * 101 + 4 * k4 + 0];
      float hk1 = h2s[r * 101 + 4 * k4 + 1];
      float hk2 = h2s[r * 101 + 4 * k4 + 2];
      float hk3 = h2s[r * 101 + 4 * k4 + 3];
      float4 wv;
      wv = v0[k4]; a0 += hk0 * wv.x + hk1 * wv.y + hk2 * wv.z + hk3 * wv.w;
      wv = v1[k4]; a1 += hk0 * wv.x + hk1 * wv.y + hk2 * wv.z + hk3 * wv.w;
      wv = v2[k4]; a2 += hk0 * wv.x + hk1 * wv.y + hk2 * wv.z + hk3 * wv.w;
      wv = v3[k4]; a3 += hk0 * wv.x + hk1 * wv.y + hk2 * wv.z + hk3 * wv.w;
    }
    float ig = sigm(a0), fg = sigm(a1), gg = tanha(a2), og = sigm(a3);
    float cn = fg * c2s[r * 101 + u] + ig * gg;
    float h2v = og * tanha(cn);
    atomicAdd(&facc[r], h2v * fcw[u]);
  }
  __syncthreads();
  if (tid < BM) out[gbase + tid] = sigm(facc[tid] + fcb0);
}

extern "C" void kernel_launch(void* const* d_in, const int* in_sizes, int n_in,
                              void* d_out, int out_size, void* d_ws, size_t ws_size,
                              hipStream_t stream) {
  const float* x    = (const float*)d_in[0];
  const float* Wih1 = (const float*)d_in[1];
  const float* Whh1 = (const float*)d_in[2];
  const float* bih1 = (const float*)d_in[3];
  const float* bhh1 = (const float*)d_in[4];
  const float* Wih2 = (const float*)d_in[5];
  const float* Whh2 = (const float*)d_in[6];
  const float* bih2 = (const float*)d_in[7];
  const float* bhh2 = (const float*)d_in[8];
  const float* fcw  = (const float*)d_in[9];
  const float* fcb  = (const float*)d_in[10];
  const float* h10  = (const float*)d_in[11];
  const float* c10  = (const float*)d_in[12];
  const float* h20  = (const float*)d_in[13];
  const float* c20  = (const float*)d_in[14];
  float* out = (float*)d_out;

  bf16_t* Wcat = (bf16_t*)d_ws;
  float* bcat = (float*)((char*)d_ws + (size_t)G1C * KPAD * sizeof(bf16_t));

  prep_kernel<<<256, 256, 0, stream>>>(Wih1, Whh1, bih1, bhh1, Wcat, bcat);
  lstm_main<<<BTOT / BM, 1024, 0, stream>>>(x, Wcat, bcat, h10, c10,
                                            Wih2, Whh2, bih2, bhh2,
                                            fcw, fcb, h20, c20, out);
}

// Round 11
// 1051.778 us; speedup vs baseline: 1.2880x; 1.2880x over previous
//
#include <hip/hip_runtime.h>
#include <hip/hip_bf16.h>

// Problem constants
#define BTOT 8192
#define TSTEPS 50
#define FIN 25
#define H1C 200
#define H2C 100
#define BM 32        // batch rows per block
#define KP 240       // stored K: 200(h) + 25(x) + 15 zeros (multiple of 16)
#define NKT 15       // K chunks of 16
#define AST2 248     // As row stride in bf16 elems (496 B, 16B-aligned rows)
#define NT 25        // 32-col output tiles
#define NREG 16      // tiles 0..15 pinned in registers (one per wave)
#define NLDS 9       // tiles 16..24 pinned in LDS
#define WTELEM 7680  // bf16 elems per W tile = NKT*512
#define AS_BYTES (BM * AST2 * 2)          // 15,872
#define WL_BYTES (NLDS * WTELEM * 2)      // 138,240

typedef __bf16 bf16_t;
typedef __bf16 bf16x8 __attribute__((ext_vector_type(8)));
typedef float f32x16 __attribute__((ext_vector_type(16)));

__device__ __forceinline__ float sigm(float x) {
  float e = __builtin_amdgcn_exp2f(-1.4426950408889634f * x);
  return __builtin_amdgcn_rcpf(1.0f + e);
}
__device__ __forceinline__ float tanha(float x) {
  float e = __builtin_amdgcn_exp2f(-2.885390081777927f * x);
  return 2.0f * __builtin_amdgcn_rcpf(1.0f + e) - 1.0f;
}

// Wcat layout: [tile(25)][kt(15)][lane(64)][elem(8)] bf16, lane = h5*32 + l31.
// Lane (l31,h5) frag kt supplies B[k=kt*16+h5*8+e][col=tile*32+l31].
// col -> unit u=tile*8+(l31>>2), gate g=l31&3 (PyTorch i,f,g,o), W row = g*200+u.
// K layout: [W_hh1(200) | W_ih1(25) | zeros(15)]
__global__ void prep_kernel(const float* __restrict__ Wih1, const float* __restrict__ Whh1,
                            const float* __restrict__ bih1, const float* __restrict__ bhh1,
                            bf16_t* __restrict__ Wcat, float* __restrict__ bcat) {
  int tid = blockIdx.x * blockDim.x + threadIdx.x;
  for (int e = tid; e < NT * WTELEM; e += gridDim.x * blockDim.x) {
    int tile = e / WTELEM;
    int rem = e - tile * WTELEM;
    int kt = rem >> 9;
    int slot = (rem >> 3) & 63;
    int elem = rem & 7;
    int l31 = slot & 31, h5 = slot >> 5;
    int k = kt * 16 + h5 * 8 + elem;
    int u = tile * 8 + (l31 >> 2);
    int gate = l31 & 3;
    int orig = gate * 200 + u;
    float v = 0.f;
    if (k < 200) v = Whh1[orig * 200 + k];
    else if (k < 225) v = Wih1[orig * 25 + (k - 200)];
    Wcat[e] = (bf16_t)v;
  }
  if (tid < 4 * H1C) {
    int n = tid;
    int tile = n >> 5, local = n & 31;
    int u = tile * 8 + (local >> 2);
    int gate = local & 3;
    int orig = gate * 200 + u;
    bcat[n] = bih1[orig] + bhh1[orig];
  }
}

// Gate gather via quad shfl_xor + LSTM cell; hv returned in regs (no LDS write).
__device__ __forceinline__ void cell_update(const f32x16& A, float* cc, float* hv, int p) {
  #pragma unroll
  for (int i = 0; i < 4; ++i) {
    float s0 = A[i], s1 = A[4 + i], s2 = A[8 + i], s3 = A[12 + i];
    float own = (p == 0) ? s0 : (p == 1) ? s1 : (p == 2) ? s2 : s3;
    int q1 = p ^ 1;
    float t1 = (q1 == 0) ? s0 : (q1 == 1) ? s1 : (q1 == 2) ? s2 : s3;
    float r1 = __shfl_xor(t1, 1);
    int q2 = p ^ 2;
    float t2 = (q2 == 0) ? s0 : (q2 == 1) ? s1 : (q2 == 2) ? s2 : s3;
    float r2 = __shfl_xor(t2, 2);
    int q3 = p ^ 3;
    float t3 = (q3 == 0) ? s0 : (q3 == 1) ? s1 : (q3 == 2) ? s2 : s3;
    float r3 = __shfl_xor(t3, 3);
    float vi = (p == 0) ? own : (p == 1) ? r1 : (p == 2) ? r2 : r3;
    float vf = (p == 0) ? r1 : (p == 1) ? own : (p == 2) ? r3 : r2;
    float vg = (p == 0) ? r2 : (p == 1) ? r3 : (p == 2) ? own : r1;
    float vo = (p == 0) ? r3 : (p == 1) ? r2 : (p == 2) ? r1 : own;
    float ig = sigm(vi), fg = sigm(vf), gg = tanha(vg), og = sigm(vo);
    float cn = fg * cc[i] + ig * gg;
    cc[i] = cn;
    hv[i] = og * tanha(cn);
  }
}

__global__ __launch_bounds__(1024, 4) void lstm_main(
    const float* __restrict__ x,
    const bf16_t* __restrict__ Wcat, const float* __restrict__ bcat,
    const float* __restrict__ h10, const float* __restrict__ c10,
    const float* __restrict__ Wih2, const float* __restrict__ Whh2,
    const float* __restrict__ bih2, const float* __restrict__ bhh2,
    const float* __restrict__ fcw, const float* __restrict__ fcb,
    const float* __restrict__ h20, const float* __restrict__ c20,
    float* __restrict__ out) {

  // smem: [As 15,872 B][Wlds 138,240 B]; layer-2 scratch overlays Wlds post-loop.
  __shared__ __align__(16) unsigned char smem[AS_BYTES + WL_BYTES];
  bf16_t* As = (bf16_t*)smem;                       // [32][248] h(0..199)|x(200..224)|0
  bf16_t* Wl = (bf16_t*)(smem + AS_BYTES);          // 9 tiles, frag-linear
  float* h2s = (float*)(smem + AS_BYTES);           // overlay (post-recurrence only)
  float* c2s = h2s + BM * 101;
  float* facc = c2s + BM * 101;

  const int tid = threadIdx.x;
  const int lane = tid & 63;
  const int wid = tid >> 6;               // 0..15
  const int gbase = blockIdx.x * BM;

  const int l31 = lane & 31;
  const int h5 = lane >> 5;
  const int p = lane & 3;                 // gate quad position
  const int uq = l31 >> 2;                // unit-in-tile 0..7
  const bool has2 = (wid < NLDS);         // waves 0..8 also own LDS tile 16+wid
  const int u1 = wid * 8 + uq;
  const int u2 = (NREG + wid) * 8 + uq;

  const bf16x8* __restrict__ Wv8 = (const bf16x8*)Wcat;

  // ---- prologue ----
  for (int i = tid; i < BM * AST2; i += 1024) As[i] = (bf16_t)0.f;

  // pin reg tile (tile wid), fill LDS tile (tile 16+wid) — one time
  bf16x8 breg[NKT];
  #pragma unroll
  for (int kt = 0; kt < NKT; ++kt) breg[kt] = Wv8[wid * (NKT * 64) + kt * 64 + lane];
  if (has2) {
    #pragma unroll
    for (int kt = 0; kt < NKT; ++kt) {
      bf16x8 f = Wv8[(NREG + wid) * (NKT * 64) + kt * 64 + lane];
      *(bf16x8*)(Wl + wid * WTELEM + kt * 512 + lane * 8) = f;
    }
  }
  __syncthreads();   // As zeroed before staging h0/x0

  for (int i = tid; i < BM * H1C; i += 1024) {
    int r = i / H1C, u = i - r * H1C;
    As[r * AST2 + u] = (bf16_t)h10[(gbase + r) * H1C + u];
  }
  if (tid < BM * FIN) {
    int r = tid / FIN, f = tid - (tid / FIN) * FIN;
    As[r * AST2 + 200 + f] = (bf16_t)x[(size_t)(gbase + r) * (TSTEPS * FIN) + f];
  }

  float bv1, bv2 = 0.f;
  float cc1[4], cc2[4];
  bv1 = bcat[wid * 32 + l31];
  #pragma unroll
  for (int i = 0; i < 4; ++i) {
    int r = 8 * p + 4 * h5 + i;
    cc1[i] = c10[(gbase + r) * H1C + u1];
    cc2[i] = 0.f;
  }
  if (has2) {
    bv2 = bcat[(NREG + wid) * 32 + l31];
    #pragma unroll
    for (int i = 0; i < 4; ++i) {
      int r = 8 * p + 4 * h5 + i;
      cc2[i] = c10[(gbase + r) * H1C + u2];
    }
  }

  // x prefetch slot (800 over 1024 threads)
  const bool xvld = (tid < BM * FIN);
  unsigned xg = 0, xlo = 0;
  if (xvld) {
    int r = tid / FIN, f = tid - (tid / FIN) * FIN;
    xg = (unsigned)(gbase + r) * (TSTEPS * FIN) + f;
    xlo = (unsigned)(r * AST2 + 200 + f);
  }
  __syncthreads();

  // ---- recurrence: zero global W traffic; only x-prefetch hits memory ----
  float hv1[4], hv2[4];
  #pragma unroll 1
  for (int t = 0; t < TSTEPS; ++t) {
    float xr = 0.f;
    if (t < TSTEPS - 1 && xvld) xr = x[xg + (unsigned)(t + 1) * FIN];

    // tile 1: reg-pinned B
    f32x16 A1;
    #pragma unroll
    for (int q = 0; q < 16; ++q) A1[q] = bv1;
    #pragma unroll
    for (int kt = 0; kt < NKT; ++kt) {
      bf16x8 a = *(const bf16x8*)(As + l31 * AST2 + kt * 16 + h5 * 8);
      A1 = __builtin_amdgcn_mfma_f32_32x32x16_bf16(a, breg[kt], A1, 0, 0, 0);
    }
    cell_update(A1, cc1, hv1, p);

    // tile 2: LDS-pinned B (sequential -> acc register reuse)
    if (has2) {
      f32x16 A2;
      #pragma unroll
      for (int q = 0; q < 16; ++q) A2[q] = bv2;
      #pragma unroll
      for (int kt = 0; kt < NKT; ++kt) {
        bf16x8 a = *(const bf16x8*)(As + l31 * AST2 + kt * 16 + h5 * 8);
        bf16x8 b2 = *(const bf16x8*)(Wl + wid * WTELEM + kt * 512 + lane * 8);
        A2 = __builtin_amdgcn_mfma_f32_32x32x16_bf16(a, b2, A2, 0, 0, 0);
      }
      cell_update(A2, cc2, hv2, p);
    }

    __syncthreads();   // all As reads done
    #pragma unroll
    for (int i = 0; i < 4; ++i) {
      int row = 8 * p + 4 * h5 + i;
      As[row * AST2 + u1] = (bf16_t)hv1[i];
      if (has2) As[row * AST2 + u2] = (bf16_t)hv2[i];
    }
    if (t < TSTEPS - 1 && xvld) As[xlo] = (bf16_t)xr;
    __syncthreads();   // h_{t+1}, x_{t+1} published
  }

  const bf16_t* __restrict__ hf = As;   // final h1: rows [32], cols 0..199, stride AST2

  // ---- fused layer-2 (single LSTM cell on final h1) + FC + sigmoid ----
  for (int i = tid; i < BM * H2C; i += 1024) {
    int r = i / H2C, u = i - r * H2C;
    h2s[r * 101 + u] = h20[(gbase + r) * H2C + u];
    c2s[r * 101 + u] = c20[(gbase + r) * H2C + u];
  }
  if (tid < BM) facc[tid] = 0.f;
  __syncthreads();

  const float fcb0 = fcb[0];
  for (int i = tid; i < BM * H2C; i += 1024) {
    int u = i >> 5;       // 0..99 (consecutive threads share u -> W rows broadcast)
    int r = i & 31;
    float a0 = bih2[u] + bhh2[u];
    float a1 = bih2[100 + u] + bhh2[100 + u];
    float a2 = bih2[200 + u] + bhh2[200 + u];
    float a3 = bih2[300 + u] + bhh2[300 + u];
    const float4* w0 = (const float4*)(Wih2 + (0 * H2C + u) * H1C);
    const float4* w1 = (const float4*)(Wih2 + (1 * H2C + u) * H1C);
    const float4* w2 = (const float4*)(Wih2 + (2 * H2C + u) * H1C);
    const float4* w3 = (const float4*)(Wih2 + (3 * H2C + u) * H1C);
    #pragma unroll 5
    for (int k4 = 0; k4 < 50; ++k4) {
      float hk0 = (float)hf[r * AST2 + 4 * k4 + 0];
      float hk1 = (float)hf[r * AST2 + 4 * k4 + 1];
      float hk2 = (float)hf[r * AST2 + 4 * k4 + 2];
      float hk3 = (float)hf[r * AST2 + 4 * k4 + 3];
      float4 wv;
      wv = w0[k4]; a0 += hk0 * wv.x + hk1 * wv.y + hk2 * wv.z + hk3 * wv.w;
      wv = w1[k4]; a1 += hk0 * wv.x + hk1 * wv.y + hk2 * wv.z + hk3 * wv.w;
      wv = w2[k4]; a2 += hk0 * wv.x + hk1 * wv.y + hk2 * wv.z + hk3 * wv.w;
      wv = w3[k4]; a3 += hk0 * wv.x + hk1 * wv.y + hk2 * wv.z + hk3 * wv.w;
    }
    const float4* v0 = (const float4*)(Whh2 + (0 * H2C + u) * H2C);
    const float4* v1 = (const float4*)(Whh2 + (1 * H2C + u) * H2C);
    const float4* v2 = (const float4*)(Whh2 + (2 * H2C + u) * H2C);
    const float4* v3 = (const float4*)(Whh2 + (3 * H2C + u) * H2C);
    #pragma unroll 5
    for (int k4 = 0; k4 < 25; ++k4) {
      float hk0 = h2s[r * 101 + 4 * k4 + 0];
      float hk1 = h2s[r * 101 + 4 * k4 + 1];
      float hk2 = h2s[r * 101 + 4 * k4 + 2];
      float hk3 = h2s[r * 101 + 4 * k4 + 3];
      float4 wv;
      wv = v0[k4]; a0 += hk0 * wv.x + hk1 * wv.y + hk2 * wv.z + hk3 * wv.w;
      wv = v1[k4]; a1 += hk0 * wv.x + hk1 * wv.y + hk2 * wv.z + hk3 * wv.w;
      wv = v2[k4]; a2 += hk0 * wv.x + hk1 * wv.y + hk2 * wv.z + hk3 * wv.w;
      wv = v3[k4]; a3 += hk0 * wv.x + hk1 * wv.y + hk2 * wv.z + hk3 * wv.w;
    }
    float ig = sigm(a0), fg = sigm(a1), gg = tanha(a2), og = sigm(a3);
    float cn = fg * c2s[r * 101 + u] + ig * gg;
    float h2v = og * tanha(cn);
    atomicAdd(&facc[r], h2v * fcw[u]);
  }
  __syncthreads();
  if (tid < BM) out[gbase + tid] = sigm(facc[tid] + fcb0);
}

extern "C" void kernel_launch(void* const* d_in, const int* in_sizes, int n_in,
                              void* d_out, int out_size, void* d_ws, size_t ws_size,
                              hipStream_t stream) {
  const float* x    = (const float*)d_in[0];
  const float* Wih1 = (const float*)d_in[1];
  const float* Whh1 = (const float*)d_in[2];
  const float* bih1 = (const float*)d_in[3];
  const float* bhh1 = (const float*)d_in[4];
  const float* Wih2 = (const float*)d_in[5];
  const float* Whh2 = (const float*)d_in[6];
  const float* bih2 = (const float*)d_in[7];
  const float* bhh2 = (const float*)d_in[8];
  const float* fcw  = (const float*)d_in[9];
  const float* fcb  = (const float*)d_in[10];
  const float* h10  = (const float*)d_in[11];
  const float* c10  = (const float*)d_in[12];
  const float* h20  = (const float*)d_in[13];
  const float* c20  = (const float*)d_in[14];
  float* out = (float*)d_out;

  bf16_t* Wcat = (bf16_t*)d_ws;
  float* bcat = (float*)((char*)d_ws + (size_t)NT * WTELEM * sizeof(bf16_t));

  prep_kernel<<<256, 256, 0, stream>>>(Wih1, Whh1, bih1, bhh1, Wcat, bcat);
  lstm_main<<<BTOT / BM, 1024, 0, stream>>>(x, Wcat, bcat, h10, c10,
                                            Wih2, Whh2, bih2, bhh2,
                                            fcw, fcb, h20, c20, out);
}

// Round 12
// 1050.370 us; speedup vs baseline: 1.2897x; 1.0013x over previous
//
#include <hip/hip_runtime.h>
#include <hip/hip_bf16.h>

// Problem constants
#define BTOT 8192
#define TSTEPS 50
#define FIN 25
#define H1C 200
#define H2C 100
#define BM 32        // batch rows per block
#define KP 240       // stored K: 200(h) + 25(x) + 15 zeros (multiple of 16)
#define NKT 15       // K chunks of 16
#define AST2 248     // As row stride in bf16 elems (496 B, 16B-aligned rows)
#define NT 25        // 32-col output tiles
#define NREG 16      // tiles 0..15 pinned in registers (one per wave)
#define NLDS 9       // tiles 16..24 pinned in LDS
#define WTELEM 7680  // bf16 elems per W tile = NKT*512
#define AS_BYTES (BM * AST2 * 2)          // 15,872
#define WL_BYTES (NLDS * WTELEM * 2)      // 138,240

typedef __bf16 bf16_t;
typedef __bf16 bf16x8 __attribute__((ext_vector_type(8)));
typedef float f32x4v __attribute__((ext_vector_type(4)));
typedef float f32x16 __attribute__((ext_vector_type(16)));

__device__ __forceinline__ float sigm(float x) {
  float e = __builtin_amdgcn_exp2f(-1.4426950408889634f * x);
  return __builtin_amdgcn_rcpf(1.0f + e);
}
__device__ __forceinline__ float tanha(float x) {
  float e = __builtin_amdgcn_exp2f(-2.885390081777927f * x);
  return 2.0f * __builtin_amdgcn_rcpf(1.0f + e) - 1.0f;
}

// Wcat layout: [tile(25)][kt(15)][lane(64)][elem(8)] bf16, lane = h5*32 + l31.
// Lane (l31,h5) frag kt supplies B[k=kt*16+h5*8+e][col=tile*32+l31].
// col -> unit u=tile*8+(l31>>2), gate g=l31&3 (PyTorch i,f,g,o), W row = g*200+u.
// K layout: [W_hh1(200) | W_ih1(25) | zeros(15)]
__global__ void prep_kernel(const float* __restrict__ Wih1, const float* __restrict__ Whh1,
                            const float* __restrict__ bih1, const float* __restrict__ bhh1,
                            bf16_t* __restrict__ Wcat, float* __restrict__ bcat) {
  int tid = blockIdx.x * blockDim.x + threadIdx.x;
  for (int e = tid; e < NT * WTELEM; e += gridDim.x * blockDim.x) {
    int tile = e / WTELEM;
    int rem = e - tile * WTELEM;
    int kt = rem >> 9;
    int slot = (rem >> 3) & 63;
    int elem = rem & 7;
    int l31 = slot & 31, h5 = slot >> 5;
    int k = kt * 16 + h5 * 8 + elem;
    int u = tile * 8 + (l31 >> 2);
    int gate = l31 & 3;
    int orig = gate * 200 + u;
    float v = 0.f;
    if (k < 200) v = Whh1[orig * 200 + k];
    else if (k < 225) v = Wih1[orig * 25 + (k - 200)];
    Wcat[e] = (bf16_t)v;
  }
  if (tid < 4 * H1C) {
    int n = tid;
    int tile = n >> 5, local = n & 31;
    int u = tile * 8 + (local >> 2);
    int gate = local & 3;
    int orig = gate * 200 + u;
    bcat[n] = bih1[orig] + bhh1[orig];
  }
}

// Gate gather via quad shfl_xor + LSTM cell; hv returned in regs (no LDS write).
__device__ __forceinline__ void cell_update(const f32x16& A, float* cc, float* hv, int p) {
  #pragma unroll
  for (int i = 0; i < 4; ++i) {
    float s0 = A[i], s1 = A[4 + i], s2 = A[8 + i], s3 = A[12 + i];
    float own = (p == 0) ? s0 : (p == 1) ? s1 : (p == 2) ? s2 : s3;
    int q1 = p ^ 1;
    float t1 = (q1 == 0) ? s0 : (q1 == 1) ? s1 : (q1 == 2) ? s2 : s3;
    float r1 = __shfl_xor(t1, 1);
    int q2 = p ^ 2;
    float t2 = (q2 == 0) ? s0 : (q2 == 1) ? s1 : (q2 == 2) ? s2 : s3;
    float r2 = __shfl_xor(t2, 2);
    int q3 = p ^ 3;
    float t3 = (q3 == 0) ? s0 : (q3 == 1) ? s1 : (q3 == 2) ? s2 : s3;
    float r3 = __shfl_xor(t3, 3);
    float vi = (p == 0) ? own : (p == 1) ? r1 : (p == 2) ? r2 : r3;
    float vf = (p == 0) ? r1 : (p == 1) ? own : (p == 2) ? r3 : r2;
    float vg = (p == 0) ? r2 : (p == 1) ? r3 : (p == 2) ? own : r1;
    float vo = (p == 0) ? r3 : (p == 1) ? r2 : (p == 2) ? r1 : own;
    float ig = sigm(vi), fg = sigm(vf), gg = tanha(vg), og = sigm(vo);
    float cn = fg * cc[i] + ig * gg;
    cc[i] = cn;
    hv[i] = og * tanha(cn);
  }
}

__global__ __launch_bounds__(1024, 2) void lstm_main(
    const float* __restrict__ x,
    const bf16_t* __restrict__ Wcat, const float* __restrict__ bcat,
    const float* __restrict__ h10, const float* __restrict__ c10,
    const float* __restrict__ Wih2, const float* __restrict__ Whh2,
    const float* __restrict__ bih2, const float* __restrict__ bhh2,
    const float* __restrict__ fcw, const float* __restrict__ fcb,
    const float* __restrict__ h20, const float* __restrict__ c20,
    float* __restrict__ out) {

  // smem: [As 15,872 B][Wlds 138,240 B]; layer-2 scratch overlays Wlds post-loop.
  __shared__ __align__(16) unsigned char smem[AS_BYTES + WL_BYTES];
  bf16_t* As = (bf16_t*)smem;                       // [32][248] h(0..199)|x(200..224)|0
  bf16_t* Wl = (bf16_t*)(smem + AS_BYTES);          // 9 tiles, frag-linear
  float* h2s = (float*)(smem + AS_BYTES);           // overlay (post-recurrence only)
  float* c2s = h2s + BM * 101;
  float* facc = c2s + BM * 101;

  const int tid = threadIdx.x;
  const int lane = tid & 63;
  const int wid = tid >> 6;               // 0..15
  const int gbase = blockIdx.x * BM;

  const int l31 = lane & 31;
  const int h5 = lane >> 5;
  const int p = lane & 3;                 // gate quad position
  const int uq = l31 >> 2;                // unit-in-tile 0..7
  const bool has2 = (wid < NLDS);         // waves 0..8 also own LDS tile 16+wid
  const int u1 = wid * 8 + uq;
  const int u2 = (NREG + wid) * 8 + uq;

  const f32x4v* __restrict__ Wv4 = (const f32x4v*)Wcat;

  // ---- prologue ----
  for (int i = tid; i < BM * AST2; i += 1024) As[i] = (bf16_t)0.f;

  // pin reg tile (tile wid) — opaque asm definition prevents the allocator
  // from rematerializing these loads inside the t-loop or spilling cheaply.
  f32x4v breg[NKT];
  #pragma unroll
  for (int kt = 0; kt < NKT; ++kt) {
    breg[kt] = Wv4[wid * (NKT * 64) + kt * 64 + lane];
    asm volatile("" : "+v"(breg[kt]));
  }
  // fill LDS tile (tile 16+wid) — one time
  if (has2) {
    #pragma unroll
    for (int kt = 0; kt < NKT; ++kt) {
      f32x4v f = Wv4[(NREG + wid) * (NKT * 64) + kt * 64 + lane];
      *(f32x4v*)(Wl + wid * WTELEM + kt * 512 + lane * 8) = f;
    }
  }
  __syncthreads();   // As zeroed before staging h0/x0

  for (int i = tid; i < BM * H1C; i += 1024) {
    int r = i / H1C, u = i - r * H1C;
    As[r * AST2 + u] = (bf16_t)h10[(gbase + r) * H1C + u];
  }
  if (tid < BM * FIN) {
    int r = tid / FIN, f = tid - (tid / FIN) * FIN;
    As[r * AST2 + 200 + f] = (bf16_t)x[(size_t)(gbase + r) * (TSTEPS * FIN) + f];
  }

  float bv1, bv2 = 0.f;
  float cc1[4], cc2[4];
  bv1 = bcat[wid * 32 + l31];
  #pragma unroll
  for (int i = 0; i < 4; ++i) {
    int r = 8 * p + 4 * h5 + i;
    cc1[i] = c10[(gbase + r) * H1C + u1];
    cc2[i] = 0.f;
  }
  if (has2) {
    bv2 = bcat[(NREG + wid) * 32 + l31];
    #pragma unroll
    for (int i = 0; i < 4; ++i) {
      int r = 8 * p + 4 * h5 + i;
      cc2[i] = c10[(gbase + r) * H1C + u2];
    }
  }

  // x prefetch slot (800 over 1024 threads)
  const bool xvld = (tid < BM * FIN);
  unsigned xg = 0, xlo = 0;
  if (xvld) {
    int r = tid / FIN, f = tid - (tid / FIN) * FIN;
    xg = (unsigned)(gbase + r) * (TSTEPS * FIN) + f;
    xlo = (unsigned)(r * AST2 + 200 + f);
  }
  __syncthreads();

  // ---- recurrence: zero global W traffic; only x-prefetch hits memory ----
  float hv1[4], hv2[4];
  #pragma unroll 1
  for (int t = 0; t < TSTEPS; ++t) {
    float xr = 0.f;
    if (t < TSTEPS - 1 && xvld) xr = x[xg + (unsigned)(t + 1) * FIN];

    // tile 1: reg-pinned B
    f32x16 A1;
    #pragma unroll
    for (int q = 0; q < 16; ++q) A1[q] = bv1;
    #pragma unroll
    for (int kt = 0; kt < NKT; ++kt) {
      bf16x8 a = *(const bf16x8*)(As + l31 * AST2 + kt * 16 + h5 * 8);
      A1 = __builtin_amdgcn_mfma_f32_32x32x16_bf16(a, __builtin_bit_cast(bf16x8, breg[kt]), A1, 0, 0, 0);
    }
    cell_update(A1, cc1, hv1, p);

    // tile 2: LDS-pinned B (sequential -> acc register reuse)
    if (has2) {
      f32x16 A2;
      #pragma unroll
      for (int q = 0; q < 16; ++q) A2[q] = bv2;
      #pragma unroll
      for (int kt = 0; kt < NKT; ++kt) {
        bf16x8 a = *(const bf16x8*)(As + l31 * AST2 + kt * 16 + h5 * 8);
        bf16x8 b2 = *(const bf16x8*)(Wl + wid * WTELEM + kt * 512 + lane * 8);
        A2 = __builtin_amdgcn_mfma_f32_32x32x16_bf16(a, b2, A2, 0, 0, 0);
      }
      cell_update(A2, cc2, hv2, p);
    }

    __syncthreads();   // all As reads done
    #pragma unroll
    for (int i = 0; i < 4; ++i) {
      int row = 8 * p + 4 * h5 + i;
      As[row * AST2 + u1] = (bf16_t)hv1[i];
      if (has2) As[row * AST2 + u2] = (bf16_t)hv2[i];
    }
    if (t < TSTEPS - 1 && xvld) As[xlo] = (bf16_t)xr;
    __syncthreads();   // h_{t+1}, x_{t+1} published
  }

  const bf16_t* __restrict__ hf = As;   // final h1: rows [32], cols 0..199, stride AST2

  // ---- fused layer-2 (single LSTM cell on final h1) + FC + sigmoid ----
  for (int i = tid; i < BM * H2C; i += 1024) {
    int r = i / H2C, u = i - r * H2C;
    h2s[r * 101 + u] = h20[(gbase + r) * H2C + u];
    c2s[r * 101 + u] = c20[(gbase + r) * H2C + u];
  }
  if (tid < BM) facc[tid] = 0.f;
  __syncthreads();

  const float fcb0 = fcb[0];
  for (int i = tid; i < BM * H2C; i += 1024) {
    int u = i >> 5;       // 0..99 (consecutive threads share u -> W rows broadcast)
    int r = i & 31;
    float a0 = bih2[u] + bhh2[u];
    float a1 = bih2[100 + u] + bhh2[100 + u];
    float a2 = bih2[200 + u] + bhh2[200 + u];
    float a3 = bih2[300 + u] + bhh2[300 + u];
    const float4* w0 = (const float4*)(Wih2 + (0 * H2C + u) * H1C);
    const float4* w1 = (const float4*)(Wih2 + (1 * H2C + u) * H1C);
    const float4* w2 = (const float4*)(Wih2 + (2 * H2C + u) * H1C);
    const float4* w3 = (const float4*)(Wih2 + (3 * H2C + u) * H1C);
    #pragma unroll 5
    for (int k4 = 0; k4 < 50; ++k4) {
      float hk0 = (float)hf[r * AST2 + 4 * k4 + 0];
      float hk1 = (float)hf[r * AST2 + 4 * k4 + 1];
      float hk2 = (float)hf[r * AST2 + 4 * k4 + 2];
      float hk3 = (float)hf[r * AST2 + 4 * k4 + 3];
      float4 wv;
      wv = w0[k4]; a0 += hk0 * wv.x + hk1 * wv.y + hk2 * wv.z + hk3 * wv.w;
      wv = w1[k4]; a1 += hk0 * wv.x + hk1 * wv.y + hk2 * wv.z + hk3 * wv.w;
      wv = w2[k4]; a2 += hk0 * wv.x + hk1 * wv.y + hk2 * wv.z + hk3 * wv.w;
      wv = w3[k4]; a3 += hk0 * wv.x + hk1 * wv.y + hk2 * wv.z + hk3 * wv.w;
    }
    const float4* v0 = (const float4*)(Whh2 + (0 * H2C + u) * H2C);
    const float4* v1 = (const float4*)(Whh2 + (1 * H2C + u) * H2C);
    const float4* v2 = (const float4*)(Whh2 + (2 * H2C + u) * H2C);
    const float4* v3 = (const float4*)(Whh2 + (3 * H2C + u) * H2C);
    #pragma unroll 5
    for (int k4 = 0; k4 < 25; ++k4) {
      float hk0 = h2s[r * 101 + 4 * k4 + 0];
      float hk1 = h2s[r * 101 + 4 * k4 + 1];
      float hk2 = h2s[r * 101 + 4 * k4 + 2];
      float hk3 = h2s[r * 101 + 4 * k4 + 3];
      float4 wv;
      wv = v0[k4]; a0 += hk0 * wv.x + hk1 * wv.y + hk2 * wv.z + hk3 * wv.w;
      wv = v1[k4]; a1 += hk0 * wv.x + hk1 * wv.y + hk2 * wv.z + hk3 * wv.w;
      wv = v2[k4]; a2 += hk0 * wv.x + hk1 * wv.y + hk2 * wv.z + hk3 * wv.w;
      wv = v3[k4]; a3 += hk0 * wv.x + hk1 * wv.y + hk2 * wv.z + hk3 * wv.w;
    }
    float ig = sigm(a0), fg = sigm(a1), gg = tanha(a2), og = sigm(a3);
    float cn = fg * c2s[r * 101 + u] + ig * gg;
    float h2v = og * tanha(cn);
    atomicAdd(&facc[r], h2v * fcw[u]);
  }
  __syncthreads();
  if (tid < BM) out[gbase + tid] = sigm(facc[tid] + fcb0);
}

extern "C" void kernel_launch(void* const* d_in, const int* in_sizes, int n_in,
                              void* d_out, int out_size, void* d_ws, size_t ws_size,
                              hipStream_t stream) {
  const float* x    = (const float*)d_in[0];
  const float* Wih1 = (const float*)d_in[1];
  const float* Whh1 = (const float*)d_in[2];
  const float* bih1 = (const float*)d_in[3];
  const float* bhh1 = (const float*)d_in[4];
  const float* Wih2 = (const float*)d_in[5];
  const float* Whh2 = (const float*)d_in[6];
  const float* bih2 = (const float*)d_in[7];
  const float* bhh2 = (const float*)d_in[8];
  const float* fcw  = (const float*)d_in[9];
  const float* fcb  = (const float*)d_in[10];
  const float* h10  = (const float*)d_in[11];
  const float* c10  = (const float*)d_in[12];
  const float* h20  = (const float*)d_in[13];
  const float* c20  = (const float*)d_in[14];
  float* out = (float*)d_out;

  bf16_t* Wcat = (bf16_t*)d_ws;
  float* bcat = (float*)((char*)d_ws + (size_t)NT * WTELEM * sizeof(bf16_t));

  prep_kernel<<<256, 256, 0, stream>>>(Wih1, Whh1, bih1, bhh1, Wcat, bcat);
  lstm_main<<<BTOT / BM, 1024, 0, stream>>>(x, Wcat, bcat, h10, c10,
                                            Wih2, Whh2, bih2, bhh2,
                                            fcw, fcb, h20, c20, out);
}